// Round 1
// baseline (584.443 us; speedup 1.0000x reference)
//
#include <hip/hip_runtime.h>
#include <stdint.h>

#define MDIM 8192
#define KDIM 4096
#define NDIM 4096
#define BM 128
#define BN 128
#define BK 64

typedef int v4i __attribute__((ext_vector_type(4)));

// ---------------- absmax (per-tensor) ----------------
__global__ void absmax_kernel(const float* __restrict__ src, int n4,
                              unsigned* __restrict__ out_bits) {
    int idx = blockIdx.x * blockDim.x + threadIdx.x;
    int stride = gridDim.x * blockDim.x;
    const float4* s4 = (const float4*)src;
    float m = 0.0f;
    for (int i = idx; i < n4; i += stride) {
        float4 v = s4[i];
        m = fmaxf(m, fmaxf(fmaxf(fabsf(v.x), fabsf(v.y)),
                           fmaxf(fabsf(v.z), fabsf(v.w))));
    }
#pragma unroll
    for (int off = 32; off > 0; off >>= 1)
        m = fmaxf(m, __shfl_down(m, off, 64));
    if ((threadIdx.x & 63) == 0)
        atomicMax(out_bits, __float_as_uint(m));  // |x| >= 0: uint order == float order
}

// ---------------- quantize fp32 -> int8 ----------------
__global__ void quantize_kernel(const float* __restrict__ src, int n4,
                                const unsigned* __restrict__ bits,
                                int* __restrict__ dst) {
    float amax = __uint_as_float(*bits);
    float scale = (amax > 0.0f) ? (amax / 127.0f) : 1.0f;
    int idx = blockIdx.x * blockDim.x + threadIdx.x;
    int stride = gridDim.x * blockDim.x;
    const float4* s4 = (const float4*)src;
    for (int i = idx; i < n4; i += stride) {
        float4 v = s4[i];
        int a = __float2int_rn(v.x / scale);  // IEEE div + round-half-even == jnp.round(t/scale)
        int b = __float2int_rn(v.y / scale);
        int c = __float2int_rn(v.z / scale);
        int d = __float2int_rn(v.w / scale);
        a = min(127, max(-127, a));
        b = min(127, max(-127, b));
        c = min(127, max(-127, c));
        d = min(127, max(-127, d));
        dst[i] = (a & 0xFF) | ((b & 0xFF) << 8) | ((c & 0xFF) << 16) | ((d & 0xFF) << 24);
    }
}

// ---------------- int8 GEMM: C = Aq[M,K] . Wq[N,K]^T, dequant + bias ----------------
__global__ __launch_bounds__(256) void gemm_i8(
    const signed char* __restrict__ Aq,
    const signed char* __restrict__ Wq,
    const float* __restrict__ bias,
    const unsigned* __restrict__ bits,
    float* __restrict__ out) {
    __shared__ __align__(16) signed char As[BM * BK];  // 8 KB
    __shared__ __align__(16) signed char Bs[BN * BK];  // 8 KB

    const int tid  = threadIdx.x;
    const int lane = tid & 63;
    const int wave = tid >> 6;
    const int wm = wave >> 1;  // 0..1
    const int wn = wave & 1;   // 0..1
    const int l15 = lane & 15;
    const int l4  = lane >> 4;  // 0..3

    const int m0 = blockIdx.y * BM;
    const int n0 = blockIdx.x * BN;

    // staging: chunk c covers tile row c>>2, 16B col group (c&3)*16; LDS dst = tile + c*16
    const int sr = tid >> 2;          // 0..63
    const int sc = (tid & 3) << 4;    // 0/16/32/48

    const signed char* a0 = Aq + (size_t)(m0 + sr) * KDIM + sc;
    const signed char* a1 = Aq + (size_t)(m0 + 64 + sr) * KDIM + sc;
    const signed char* b0 = Wq + (size_t)(n0 + sr) * KDIM + sc;
    const signed char* b1 = Wq + (size_t)(n0 + 64 + sr) * KDIM + sc;

    v4i acc[4][4] = {};

    for (int kb = 0; kb < KDIM; kb += BK) {
        __builtin_amdgcn_global_load_lds(
            (const __attribute__((address_space(1))) void*)(a0 + kb),
            (__attribute__((address_space(3))) void*)(As + tid * 16), 16, 0, 0);
        __builtin_amdgcn_global_load_lds(
            (const __attribute__((address_space(1))) void*)(a1 + kb),
            (__attribute__((address_space(3))) void*)(As + 4096 + tid * 16), 16, 0, 0);
        __builtin_amdgcn_global_load_lds(
            (const __attribute__((address_space(1))) void*)(b0 + kb),
            (__attribute__((address_space(3))) void*)(Bs + tid * 16), 16, 0, 0);
        __builtin_amdgcn_global_load_lds(
            (const __attribute__((address_space(1))) void*)(b1 + kb),
            (__attribute__((address_space(3))) void*)(Bs + 4096 + tid * 16), 16, 0, 0);
        __syncthreads();

        v4i af[4], bf[4];
#pragma unroll
        for (int t = 0; t < 4; ++t) {
            // A-frag: A[m = l15][k = l4*16 + j], 16 contiguous int8 -> ds_read_b128
            af[t] = *(const v4i*)(As + (wm * 64 + t * 16 + l15) * BK + l4 * 16);
            bf[t] = *(const v4i*)(Bs + (wn * 64 + t * 16 + l15) * BK + l4 * 16);
        }
#pragma unroll
        for (int i = 0; i < 4; ++i)
#pragma unroll
            for (int j = 0; j < 4; ++j)
                acc[i][j] = __builtin_amdgcn_mfma_i32_16x16x64_i8(af[i], bf[j], acc[i][j], 0, 0, 0);
        __syncthreads();
    }

    const float ax = __uint_as_float(bits[0]);
    const float aw = __uint_as_float(bits[1]);
    const float s = (ax / 127.0f) * (aw / 127.0f);

    // C/D layout (shape-determined, verified): col = lane&15, row = (lane>>4)*4 + reg
#pragma unroll
    for (int j = 0; j < 4; ++j) {
        const int col = n0 + wn * 64 + j * 16 + l15;
        const float bcol = bias[col];
#pragma unroll
        for (int i = 0; i < 4; ++i) {
            const int row0 = m0 + wm * 64 + i * 16 + l4 * 4;
#pragma unroll
            for (int r = 0; r < 4; ++r)
                out[(size_t)(row0 + r) * NDIM + col] = (float)acc[i][j][r] * s + bcol;
        }
    }
}

extern "C" void kernel_launch(void* const* d_in, const int* in_sizes, int n_in,
                              void* d_out, int out_size, void* d_ws, size_t ws_size,
                              hipStream_t stream) {
    const float* x    = (const float*)d_in[0];
    const float* w    = (const float*)d_in[1];
    const float* bias = (const float*)d_in[2];
    float* out = (float*)d_out;

    unsigned* bits = (unsigned*)d_ws;                 // [0]=absmax(x), [1]=absmax(w)
    signed char* xq = (signed char*)d_ws + 64;        // M*K int8 = 32 MB
    signed char* wq = xq + (size_t)MDIM * KDIM;       // N*K int8 = 16 MB

    hipMemsetAsync(d_ws, 0, 64, stream);

    absmax_kernel<<<2048, 256, 0, stream>>>(x, MDIM * KDIM / 4, bits);
    absmax_kernel<<<1024, 256, 0, stream>>>(w, NDIM * KDIM / 4, bits + 1);
    quantize_kernel<<<4096, 256, 0, stream>>>(x, MDIM * KDIM / 4, bits, (int*)xq);
    quantize_kernel<<<2048, 256, 0, stream>>>(w, NDIM * KDIM / 4, bits + 1, (int*)wq);

    dim3 grid(NDIM / BN, MDIM / BM);
    gemm_i8<<<grid, 256, 0, stream>>>(xq, wq, bias, bits, out);
}

// Round 2
// 461.830 us; speedup vs baseline: 1.2655x; 1.2655x over previous
//
#include <hip/hip_runtime.h>
#include <stdint.h>

#define MDIM 8192
#define KDIM 4096
#define NDIM 4096
#define BM 256
#define BN 128
#define BK 64

typedef int v4i __attribute__((ext_vector_type(4)));

// ---------------- absmax (per-tensor): one atomic per BLOCK ----------------
__global__ void absmax_kernel(const float* __restrict__ src, int n4,
                              unsigned* __restrict__ out_bits) {
    __shared__ float smax[4];
    int idx = blockIdx.x * blockDim.x + threadIdx.x;
    int stride = gridDim.x * blockDim.x;
    const float4* s4 = (const float4*)src;
    float m = 0.0f;
    for (int i = idx; i < n4; i += stride) {
        float4 v = s4[i];
        m = fmaxf(m, fmaxf(fmaxf(fabsf(v.x), fabsf(v.y)),
                           fmaxf(fabsf(v.z), fabsf(v.w))));
    }
#pragma unroll
    for (int off = 32; off > 0; off >>= 1)
        m = fmaxf(m, __shfl_down(m, off, 64));
    if ((threadIdx.x & 63) == 0) smax[threadIdx.x >> 6] = m;
    __syncthreads();
    if (threadIdx.x == 0) {
        float bm = fmaxf(fmaxf(smax[0], smax[1]), fmaxf(smax[2], smax[3]));
        atomicMax(out_bits, __float_as_uint(bm));  // |x| >= 0: uint order == float order
    }
}

// ---------------- quantize fp32 -> int8 ----------------
__global__ void quantize_kernel(const float* __restrict__ src, int n4,
                                const unsigned* __restrict__ bits,
                                int* __restrict__ dst) {
    float amax = __uint_as_float(*bits);
    float scale = (amax > 0.0f) ? (amax / 127.0f) : 1.0f;
    int idx = blockIdx.x * blockDim.x + threadIdx.x;
    int stride = gridDim.x * blockDim.x;
    const float4* s4 = (const float4*)src;
    for (int i = idx; i < n4; i += stride) {
        float4 v = s4[i];
        int a = __float2int_rn(v.x / scale);  // IEEE div + rn == jnp.round(t/scale)
        int b = __float2int_rn(v.y / scale);
        int c = __float2int_rn(v.z / scale);
        int d = __float2int_rn(v.w / scale);
        a = min(127, max(-127, a));
        b = min(127, max(-127, b));
        c = min(127, max(-127, c));
        d = min(127, max(-127, d));
        dst[i] = (a & 0xFF) | ((b & 0xFF) << 8) | ((c & 0xFF) << 16) | ((d & 0xFF) << 24);
    }
}

// ---------------- int8 GEMM: C = Aq[M,K] . Wq[N,K]^T, dequant + bias ----------------
// BM=256, BN=128, 4 waves, wave-tile 128x64 (8x4 of 16x16x64 MFMA)
__global__ __launch_bounds__(256, 2) void gemm_i8(
    const signed char* __restrict__ Aq,
    const signed char* __restrict__ Wq,
    const float* __restrict__ bias,
    const unsigned* __restrict__ bits,
    float* __restrict__ out) {
    __shared__ __align__(16) signed char As[BM * BK];  // 16 KB
    __shared__ __align__(16) signed char Bs[BN * BK];  // 8 KB

    const int tid  = threadIdx.x;
    const int lane = tid & 63;
    const int wave = tid >> 6;
    const int wm = wave >> 1;  // 0..1 -> M half (128 rows each)
    const int wn = wave & 1;   // 0..1 -> N half (64 cols each)
    const int l15 = lane & 15;
    const int l4  = lane >> 4;  // 0..3

    const int m0 = blockIdx.y * BM;
    const int n0 = blockIdx.x * BN;

    // staging: 256 threads x 16B = 4KB per call; row = g*64 + (tid>>2), colgrp = (tid&3)*16
    const int sr = tid >> 2;
    const int sc = (tid & 3) << 4;

    const signed char* aG[4];
#pragma unroll
    for (int g = 0; g < 4; ++g)
        aG[g] = Aq + (size_t)(m0 + g * 64 + sr) * KDIM + sc;
    const signed char* bG[2];
#pragma unroll
    for (int g = 0; g < 2; ++g)
        bG[g] = Wq + (size_t)(n0 + g * 64 + sr) * KDIM + sc;

    v4i acc[8][4] = {};

    for (int kb = 0; kb < KDIM; kb += BK) {
#pragma unroll
        for (int g = 0; g < 4; ++g)
            __builtin_amdgcn_global_load_lds(
                (const __attribute__((address_space(1))) void*)(aG[g] + kb),
                (__attribute__((address_space(3))) void*)(As + g * 4096 + tid * 16), 16, 0, 0);
#pragma unroll
        for (int g = 0; g < 2; ++g)
            __builtin_amdgcn_global_load_lds(
                (const __attribute__((address_space(1))) void*)(bG[g] + kb),
                (__attribute__((address_space(3))) void*)(Bs + g * 4096 + tid * 16), 16, 0, 0);
        __syncthreads();

        v4i af[8], bf[4];
#pragma unroll
        for (int t = 0; t < 8; ++t)
            af[t] = *(const v4i*)(As + (wm * 128 + t * 16 + l15) * BK + l4 * 16);
#pragma unroll
        for (int t = 0; t < 4; ++t)
            bf[t] = *(const v4i*)(Bs + (wn * 64 + t * 16 + l15) * BK + l4 * 16);

#pragma unroll
        for (int i = 0; i < 8; ++i)
#pragma unroll
            for (int j = 0; j < 4; ++j)
                acc[i][j] = __builtin_amdgcn_mfma_i32_16x16x64_i8(af[i], bf[j], acc[i][j], 0, 0, 0);
        __syncthreads();
    }

    const float ax = __uint_as_float(bits[0]);
    const float aw = __uint_as_float(bits[1]);
    const float s = (ax / 127.0f) * (aw / 127.0f);

    // C/D layout: col = lane&15, row = (lane>>4)*4 + reg
#pragma unroll
    for (int j = 0; j < 4; ++j) {
        const int col = n0 + wn * 64 + j * 16 + l15;
        const float bcol = bias[col];
#pragma unroll
        for (int i = 0; i < 8; ++i) {
            const int row0 = m0 + wm * 128 + i * 16 + l4 * 4;
#pragma unroll
            for (int r = 0; r < 4; ++r)
                out[(size_t)(row0 + r) * NDIM + col] = (float)acc[i][j][r] * s + bcol;
        }
    }
}

extern "C" void kernel_launch(void* const* d_in, const int* in_sizes, int n_in,
                              void* d_out, int out_size, void* d_ws, size_t ws_size,
                              hipStream_t stream) {
    const float* x    = (const float*)d_in[0];
    const float* w    = (const float*)d_in[1];
    const float* bias = (const float*)d_in[2];
    float* out = (float*)d_out;

    unsigned* bits = (unsigned*)d_ws;                 // [0]=absmax(x), [1]=absmax(w)
    signed char* xq = (signed char*)d_ws + 64;        // M*K int8 = 32 MB
    signed char* wq = xq + (size_t)MDIM * KDIM;       // N*K int8 = 16 MB

    hipMemsetAsync(d_ws, 0, 64, stream);

    absmax_kernel<<<1024, 256, 0, stream>>>(x, MDIM * KDIM / 4, bits);
    absmax_kernel<<<512, 256, 0, stream>>>(w, NDIM * KDIM / 4, bits + 1);
    quantize_kernel<<<2048, 256, 0, stream>>>(x, MDIM * KDIM / 4, bits, (int*)xq);
    quantize_kernel<<<1024, 256, 0, stream>>>(w, NDIM * KDIM / 4, bits + 1, (int*)wq);

    dim3 grid(NDIM / BN, MDIM / BM);
    gemm_i8<<<grid, 256, 0, stream>>>(xq, wq, bias, bits, out);
}